// Round 2
// baseline (2836.402 us; speedup 1.0000x reference)
//
#include <hip/hip_runtime.h>

#define DB 4
#define SS 4096
#define DD 1024
#define HH 16
#define HD 64
#define WW 128
#define NW 32
#define NG 32

typedef __bf16 bf16_t;
typedef bf16_t bf16x8 __attribute__((ext_vector_type(8)));
typedef float f32x4 __attribute__((ext_vector_type(4)));

static __device__ __forceinline__ f32x4 mfma16(bf16x8 a, bf16x8 b, f32x4 c) {
    return __builtin_amdgcn_mfma_f32_16x16x32_bf16(a, b, c, 0, 0, 0);
}

// ---------------- dtype probe ----------------
// If the float tensors were stored as bf16, even-indexed elements (low 16 bits
// of each u32) are N(0,1)-like. If stored as f32, those bits are mantissa
// garbage (uniform-ish exponent) -> only ~13% land in (1e-5, 1e5).
__global__ void detect_dtype(const unsigned short* __restrict__ q, int* __restrict__ flag) {
    int lane = threadIdx.x;  // 64 threads
    unsigned short u = q[2 * lane];
    bf16_t b;
    __builtin_memcpy(&b, &u, 2);
    float v = fabsf((float)b);
    bool ok = (v > 1e-5f) && (v < 1e5f);  // NaN -> false
    unsigned long long m = __ballot(ok);
    if (lane == 0) *flag = (__popcll(m) >= 32) ? 1 : 0;  // 1 = buffers are bf16
}

// ---------------- dual-dtype GEMM ----------------
// Y[m][n] = sum_k X[m][k]*Wt[n][k] + bias[n].  M=16384, N=K=1024.
// XM/WM: 0 = bf16 operand (single), 1 = f32 operand (split into hi+lo bf16).
// Skips lo*lo term. Block 256 thr = 4 waves; 64x64 block tile; 16x64 wave tile.
template <int XM, int WM, bool YF32>
static __device__ __forceinline__ void gemm_body(const void* __restrict__ Xv,
                                                 const void* __restrict__ Wv,
                                                 const void* __restrict__ Bv,
                                                 void* __restrict__ Yv) {
    const int lane = threadIdx.x & 63;
    const int wv   = threadIdx.x >> 6;
    const int c    = lane & 15;
    const int quad = lane >> 4;
    const int mbase = blockIdx.x * 64 + wv * 16;
    const int nbase = blockIdx.y * 64;

    f32x4 acc[4] = {};
    #pragma unroll 2
    for (int k0 = 0; k0 < DD; k0 += 32) {
        const int ka = k0 + quad * 8;
        bf16x8 ah, al;
        if (XM == 0) {
            ah = *(const bf16x8*)((const bf16_t*)Xv + (size_t)(mbase + c) * DD + ka);
        } else {
            const float* p = (const float*)Xv + (size_t)(mbase + c) * DD + ka;
            #pragma unroll
            for (int t = 0; t < 8; ++t) {
                float f = p[t];
                bf16_t h = (bf16_t)f;
                ah[t] = h;
                al[t] = (bf16_t)(f - (float)h);
            }
        }
        #pragma unroll
        for (int j = 0; j < 4; ++j) {
            bf16x8 bh, bl;
            if (WM == 0) {
                bh = *(const bf16x8*)((const bf16_t*)Wv + (size_t)(nbase + j * 16 + c) * DD + ka);
            } else {
                const float* p = (const float*)Wv + (size_t)(nbase + j * 16 + c) * DD + ka;
                #pragma unroll
                for (int t = 0; t < 8; ++t) {
                    float f = p[t];
                    bf16_t h = (bf16_t)f;
                    bh[t] = h;
                    bl[t] = (bf16_t)(f - (float)h);
                }
            }
            acc[j] = mfma16(ah, bh, acc[j]);
            if (WM == 1) acc[j] = mfma16(ah, bl, acc[j]);
            if (XM == 1) acc[j] = mfma16(al, bh, acc[j]);
        }
    }
    #pragma unroll
    for (int j = 0; j < 4; ++j) {
        float bb = (WM == 1) ? ((const float*)Bv)[nbase + j * 16 + c]
                             : (float)((const bf16_t*)Bv)[nbase + j * 16 + c];
        #pragma unroll
        for (int r = 0; r < 4; ++r) {
            size_t off = (size_t)(mbase + quad * 4 + r) * DD + nbase + j * 16 + c;
            float v = acc[j][r] + bb;
            if (YF32) ((float*)Yv)[off] = v;
            else      ((bf16_t*)Yv)[off] = (bf16_t)v;
        }
    }
}

// kind: 0 = projection (X dtype = flag, Y bf16), 1 = final (X bf16 ctx, Y dtype = flag)
__global__ __launch_bounds__(256) void gemm_dual(const void* __restrict__ X,
                                                 const void* __restrict__ W,
                                                 const void* __restrict__ B,
                                                 void* __restrict__ Y,
                                                 const int* __restrict__ flag, int kind) {
    if (*flag) {
        gemm_body<0, 0, false>(X, W, B, Y);      // bf16 in, bf16 out (both kinds)
    } else if (kind == 0) {
        gemm_body<1, 1, false>(X, W, B, Y);      // f32 in (split X & W), bf16 out
    } else {
        gemm_body<0, 1, true>(X, W, B, Y);       // bf16 ctx, f32 W (split), f32 out
    }
}

// ---------------- local windowed attention ----------------
__global__ __launch_bounds__(256) void attn_local(const bf16_t* __restrict__ Q,
                                                  const bf16_t* __restrict__ K,
                                                  const bf16_t* __restrict__ V,
                                                  bf16_t* __restrict__ ctx) {
    const int wx = blockIdx.x, h = blockIdx.y, b = blockIdx.z;
    const int tid  = threadIdx.x;
    const int lane = tid & 63;
    const int wv   = tid >> 6;
    const int c    = lane & 15;
    const int quad = lane >> 4;

    __shared__ alignas(16) bf16_t pbuf[128][136];  // 272B row stride = 16*17 (aligned)
    __shared__ alignas(16) bf16_t vtb[64][136];    // V^T: vtb[d][j]

    const size_t base = ((size_t)b * SS + (size_t)wx * WW) * DD + (size_t)h * HD;

    for (int e = tid; e < WW * HD; e += 256) {
        int j = e >> 6, d = e & 63;
        vtb[d][j] = V[base + (size_t)j * DD + d];
    }

    const float scale = 0.125f;

    #pragma unroll
    for (int ii = 0; ii < 2; ++ii) {
        const int it = wv * 2 + ii;
        f32x4 s[8] = {};
        #pragma unroll
        for (int kt = 0; kt < 2; ++kt) {
            bf16x8 a = *(const bf16x8*)(Q + base + (size_t)(it * 16 + c) * DD + kt * 32 + quad * 8);
            #pragma unroll
            for (int jt = 0; jt < 8; ++jt) {
                bf16x8 bb = *(const bf16x8*)(K + base + (size_t)(jt * 16 + c) * DD + kt * 32 + quad * 8);
                s[jt] = mfma16(a, bb, s[jt]);
            }
        }
        #pragma unroll
        for (int jt = 0; jt < 8; ++jt) s[jt] *= scale;

        #pragma unroll
        for (int r = 0; r < 4; ++r) {
            float m = -1e30f;
            #pragma unroll
            for (int jt = 0; jt < 8; ++jt) m = fmaxf(m, s[jt][r]);
            #pragma unroll
            for (int off = 1; off < 16; off <<= 1) m = fmaxf(m, __shfl_xor(m, off));
            float p[8], sum = 0.f;
            #pragma unroll
            for (int jt = 0; jt < 8; ++jt) { p[jt] = __expf(s[jt][r] - m); sum += p[jt]; }
            #pragma unroll
            for (int off = 1; off < 16; off <<= 1) sum += __shfl_xor(sum, off);
            float inv = 1.0f / sum;
            int row = it * 16 + quad * 4 + r;
            #pragma unroll
            for (int jt = 0; jt < 8; ++jt) pbuf[row][jt * 16 + c] = (bf16_t)(p[jt] * inv);
        }
    }

    __syncthreads();

    #pragma unroll
    for (int ii = 0; ii < 2; ++ii) {
        const int it = wv * 2 + ii;
        f32x4 o[4] = {};
        #pragma unroll
        for (int kt = 0; kt < 4; ++kt) {
            bf16x8 a = *(const bf16x8*)&pbuf[it * 16 + c][kt * 32 + quad * 8];
            #pragma unroll
            for (int dt = 0; dt < 4; ++dt) {
                bf16x8 bb = *(const bf16x8*)&vtb[dt * 16 + c][kt * 32 + quad * 8];
                o[dt] = mfma16(a, bb, o[dt]);
            }
        }
        #pragma unroll
        for (int dt = 0; dt < 4; ++dt)
            #pragma unroll
            for (int r = 0; r < 4; ++r)
                ctx[base + (size_t)(it * 16 + quad * 4 + r) * DD + dt * 16 + c] = (bf16_t)(o[dt][r]);
    }
}

// ---------------- global-token attention (overwrites ctx rows) ----------------
__global__ __launch_bounds__(256) void attn_global(const bf16_t* __restrict__ Q,
                                                   const bf16_t* __restrict__ K,
                                                   const bf16_t* __restrict__ V,
                                                   const int* __restrict__ gidx,
                                                   bf16_t* __restrict__ ctx) {
    const int h = blockIdx.x, b = blockIdx.y;
    const int tid = threadIdx.x;

    __shared__ float qs[NG][HD], ks[NG][HD], vs[NG][HD];
    __shared__ float sc[NG][NG + 1];
    __shared__ int gi[NG];

    if (tid < NG) gi[tid] = gidx[tid];
    __syncthreads();

    for (int e = tid; e < NG * HD; e += 256) {
        int i = e >> 6, d = e & 63;
        size_t off = ((size_t)b * SS + gi[i]) * DD + (size_t)h * HD + d;
        qs[i][d] = (float)Q[off];
        ks[i][d] = (float)K[off];
        vs[i][d] = (float)V[off];
    }
    __syncthreads();

    for (int e = tid; e < NG * NG; e += 256) {
        int i = e >> 5, j = e & 31;
        float s = 0.f;
        #pragma unroll 8
        for (int d = 0; d < HD; ++d) s += qs[i][d] * ks[j][d];
        sc[i][j] = s * 0.125f;
    }
    __syncthreads();

    if (tid < NG) {
        float m = -1e30f;
        for (int j = 0; j < NG; ++j) m = fmaxf(m, sc[tid][j]);
        float sum = 0.f;
        for (int j = 0; j < NG; ++j) { float p = __expf(sc[tid][j] - m); sc[tid][j] = p; sum += p; }
        float inv = 1.f / sum;
        for (int j = 0; j < NG; ++j) sc[tid][j] *= inv;
    }
    __syncthreads();

    for (int e = tid; e < NG * HD; e += 256) {
        int i = e >> 6, d = e & 63;
        float o = 0.f;
        #pragma unroll 8
        for (int j = 0; j < NG; ++j) o += sc[i][j] * vs[j][d];
        ctx[((size_t)b * SS + gi[i]) * DD + (size_t)h * HD + d] = (bf16_t)o;
    }
}

// ---------------- staging copy: ws -> d_out, dtype per flag ----------------
__global__ void copy_out(const unsigned int* __restrict__ src, unsigned int* __restrict__ dst,
                         const int* __restrict__ flag, int out_elems) {
    int nwords = (*flag) ? (out_elems >> 1) : out_elems;  // bf16: 2B/elem, f32: 4B/elem
    for (int i = blockIdx.x * blockDim.x + threadIdx.x; i < nwords; i += gridDim.x * blockDim.x)
        dst[i] = src[i];
}

extern "C" void kernel_launch(void* const* d_in, const int* in_sizes, int n_in,
                              void* d_out, int out_size, void* d_ws, size_t ws_size,
                              hipStream_t stream) {
    const void* query = d_in[0];
    const void* key_  = d_in[1];
    const void* value = d_in[2];
    const void* Wq = d_in[3];  const void* bq = d_in[4];
    const void* Wk = d_in[5];  const void* bk = d_in[6];
    const void* Wv = d_in[7];  const void* bv = d_in[8];
    const void* Wo = d_in[9];  const void* bo = d_in[10];
    const int* gidx = (const int*)d_in[11];

    const size_t nTok = (size_t)DB * SS * DD;  // 16,777,216

    int* flag = (int*)d_ws;
    char* wsb = (char*)d_ws + 1024;
    bf16_t* Qp = (bf16_t*)wsb;            // 32 MB
    bf16_t* Kp = Qp + nTok;               // 32 MB
    bf16_t* Vp = Kp + nTok;               // 32 MB
    void* Ybuf = (void*)wsb;              // final-gemm out, overlaps dead Qp/Kp (<=64 MB)
    bf16_t* ctx = (bf16_t*)d_out;         // ctx staged in d_out (32 MB bf16, fits either dtype)

    detect_dtype<<<1, 64, 0, stream>>>((const unsigned short*)query, flag);

    dim3 gg(DB * SS / 64, DD / 64);  // (256, 16)
    gemm_dual<<<gg, 256, 0, stream>>>(query, Wq, bq, Qp, flag, 0);
    gemm_dual<<<gg, 256, 0, stream>>>(key_,  Wk, bk, Kp, flag, 0);
    gemm_dual<<<gg, 256, 0, stream>>>(value, Wv, bv, Vp, flag, 0);
    attn_local<<<dim3(NW, HH, DB), 256, 0, stream>>>(Qp, Kp, Vp, ctx);
    attn_global<<<dim3(HH, DB), 256, 0, stream>>>(Qp, Kp, Vp, gidx, ctx);
    gemm_dual<<<gg, 256, 0, stream>>>(ctx, Wo, bo, Ybuf, flag, 1);
    copy_out<<<1024, 256, 0, stream>>>((const unsigned int*)Ybuf, (unsigned int*)d_out, flag, out_size);
}

// Round 3
// 619.015 us; speedup vs baseline: 4.5821x; 4.5821x over previous
//
#include <hip/hip_runtime.h>

#define DB 4
#define SS 4096
#define DD 1024
#define HH 16
#define HD 64
#define WW 128
#define NW 32
#define NG 32

typedef __bf16 bf16_t;
typedef bf16_t bf16x4 __attribute__((ext_vector_type(4)));
typedef bf16_t bf16x8 __attribute__((ext_vector_type(8)));
typedef float f32x4 __attribute__((ext_vector_type(4)));

typedef const __attribute__((address_space(1))) void* gptr_t;
typedef __attribute__((address_space(3))) void* lptr_t;

static __device__ __forceinline__ f32x4 mfma16(bf16x8 a, bf16x8 b, f32x4 c) {
    return __builtin_amdgcn_mfma_f32_16x16x32_bf16(a, b, c, 0, 0, 0);
}

// ---------------- dtype probe (1 = buffers are bf16, 0 = f32) ----------------
__global__ void detect_dtype(const unsigned short* __restrict__ q, int* __restrict__ flag) {
    int lane = threadIdx.x;  // 64 threads
    unsigned short u = q[2 * lane];
    bf16_t b;
    __builtin_memcpy(&b, &u, 2);
    float v = fabsf((float)b);
    bool ok = (v > 1e-5f) && (v < 1e5f);
    unsigned long long m = __ballot(ok);
    if (lane == 0) *flag = (__popcll(m) >= 32) ? 1 : 0;
}

// ---------------- conversions ----------------
__global__ void cvt_x(const void* __restrict__ src, bf16_t* __restrict__ dst,
                      const int* __restrict__ flag) {
    int i = blockIdx.x * blockDim.x + threadIdx.x;  // one per 4 elems, 4M threads
    int e = i * 4;
    if (*flag) {
        *(ushort4*)(dst + e) = ((const ushort4*)src)[i];
    } else {
        float4 f = ((const float4*)src)[i];
        bf16x4 o = { (bf16_t)f.x, (bf16_t)f.y, (bf16_t)f.z, (bf16_t)f.w };
        *(bf16x4*)(dst + e) = o;
    }
}

__global__ void cvt_w(const void* __restrict__ src, bf16_t* __restrict__ wh,
                      bf16_t* __restrict__ wl, const int* __restrict__ flag) {
    int i = blockIdx.x * blockDim.x + threadIdx.x;  // one per 4 elems, 256K threads
    int e = i * 4;
    if (*flag) {
        *(ushort4*)(wh + e) = ((const ushort4*)src)[i];
        bf16x4 z = {};
        *(bf16x4*)(wl + e) = z;
    } else {
        float4 f = ((const float4*)src)[i];
        bf16x4 h = { (bf16_t)f.x, (bf16_t)f.y, (bf16_t)f.z, (bf16_t)f.w };
        bf16x4 l = { (bf16_t)(f.x - (float)h[0]), (bf16_t)(f.y - (float)h[1]),
                     (bf16_t)(f.z - (float)h[2]), (bf16_t)(f.w - (float)h[3]) };
        *(bf16x4*)(wh + e) = h;
        *(bf16x4*)(wl + e) = l;
    }
}

__global__ void cvt_bias(const void* b0, const void* b1, const void* b2, const void* b3,
                         float* __restrict__ dst, const int* __restrict__ flag) {
    int i = blockIdx.x * blockDim.x + threadIdx.x;  // 4096
    const void* s = (i >> 10) == 0 ? b0 : (i >> 10) == 1 ? b1 : (i >> 10) == 2 ? b2 : b3;
    int j = i & 1023;
    dst[i] = (*flag) ? (float)((const bf16_t*)s)[j] : ((const float*)s)[j];
}

__global__ void expand_out(const bf16_t* __restrict__ src, void* __restrict__ dst,
                           const int* __restrict__ flag) {
    int i = blockIdx.x * blockDim.x + threadIdx.x;  // one per 4 elems
    int e = i * 4;
    ushort4 u = *(const ushort4*)(src + e);
    if (*flag) {
        ((ushort4*)dst)[i] = u;
    } else {
        const bf16x4 b = *(const bf16x4*)&u;
        float4 f = { (float)b[0], (float)b[1], (float)b[2], (float)b[3] };
        ((float4*)dst)[i] = f;
    }
}

// ---------------- m97-style split-W GEMM ----------------
// Y[m][n] = sum_k X[m][k]*(Wh[n][k]+Wl[n][k]) + bias[n],  bf16 out.
// M=16384, N=K=1024. 256 thr = 4 waves (2x2), block tile 128x128, BK=32.
__global__ __launch_bounds__(256) void gemm2(const bf16_t* __restrict__ X,
                                             const bf16_t* __restrict__ Wh,
                                             const bf16_t* __restrict__ Wl,
                                             const float* __restrict__ bias,
                                             bf16_t* __restrict__ Y) {
    __shared__ alignas(16) bf16_t sA[128 * 32];   // [row][k], 64B row stride
    __shared__ alignas(16) bf16_t sBh[128 * 32];
    __shared__ alignas(16) bf16_t sBl[128 * 32];

    const int tid  = threadIdx.x;
    const int lane = tid & 63;
    const int wv   = tid >> 6;
    const int c    = lane & 15;
    const int quad = lane >> 4;
    const int wi   = wv >> 1, wj = wv & 1;

    const int mbase = blockIdx.x * 128;
    const int nbase = blockIdx.y * 128;

    f32x4 acc[4][4] = {};

    const int gb0 = wv * 2048 + lane * 16;  // this lane's byte index in the packed 8KB tile

    for (int k0 = 0; k0 < DD; k0 += 32) {
        __syncthreads();
        #pragma unroll
        for (int j = 0; j < 2; ++j) {
            const int g = gb0 + j * 1024;
            const int row = g >> 6;       // tile row (64B per row)
            const int col = g & 63;       // byte offset within row
            const int lofs = wv * 2048 + j * 1024;  // wave-uniform LDS byte base
            const char* srcA  = (const char*)(X  + (size_t)(mbase + row) * DD + k0) + col;
            const char* srcBh = (const char*)(Wh + (size_t)(nbase + row) * DD + k0) + col;
            const char* srcBl = (const char*)(Wl + (size_t)(nbase + row) * DD + k0) + col;
            __builtin_amdgcn_global_load_lds((gptr_t)srcA,  (lptr_t)((char*)sA  + lofs), 16, 0, 0);
            __builtin_amdgcn_global_load_lds((gptr_t)srcBh, (lptr_t)((char*)sBh + lofs), 16, 0, 0);
            __builtin_amdgcn_global_load_lds((gptr_t)srcBl, (lptr_t)((char*)sBl + lofs), 16, 0, 0);
        }
        __syncthreads();

        bf16x8 af[4], bh[4], bl[4];
        #pragma unroll
        for (int t = 0; t < 4; ++t) {
            af[t] = *(const bf16x8*)&sA [(wi * 64 + t * 16 + c) * 32 + quad * 8];
            bh[t] = *(const bf16x8*)&sBh[(wj * 64 + t * 16 + c) * 32 + quad * 8];
            bl[t] = *(const bf16x8*)&sBl[(wj * 64 + t * 16 + c) * 32 + quad * 8];
        }
        #pragma unroll
        for (int ti = 0; ti < 4; ++ti)
            #pragma unroll
            for (int tj = 0; tj < 4; ++tj) {
                acc[ti][tj] = mfma16(af[ti], bh[tj], acc[ti][tj]);
                acc[ti][tj] = mfma16(af[ti], bl[tj], acc[ti][tj]);
            }
    }

    #pragma unroll
    for (int tj = 0; tj < 4; ++tj) {
        const int col = nbase + wj * 64 + tj * 16 + c;
        const float bv = bias[col];
        #pragma unroll
        for (int ti = 0; ti < 4; ++ti)
            #pragma unroll
            for (int r = 0; r < 4; ++r) {
                const int row = mbase + wi * 64 + ti * 16 + quad * 4 + r;
                Y[(size_t)row * DD + col] = (bf16_t)(acc[ti][tj][r] + bv);
            }
    }
}

// ---------------- local windowed attention (unchanged, verified) ----------------
__global__ __launch_bounds__(256) void attn_local(const bf16_t* __restrict__ Q,
                                                  const bf16_t* __restrict__ K,
                                                  const bf16_t* __restrict__ V,
                                                  bf16_t* __restrict__ ctx) {
    const int wx = blockIdx.x, h = blockIdx.y, b = blockIdx.z;
    const int tid  = threadIdx.x;
    const int lane = tid & 63;
    const int wv   = tid >> 6;
    const int c    = lane & 15;
    const int quad = lane >> 4;

    __shared__ alignas(16) bf16_t pbuf[128][136];
    __shared__ alignas(16) bf16_t vtb[64][136];

    const size_t base = ((size_t)b * SS + (size_t)wx * WW) * DD + (size_t)h * HD;

    for (int e = tid; e < WW * HD; e += 256) {
        int j = e >> 6, d = e & 63;
        vtb[d][j] = V[base + (size_t)j * DD + d];
    }

    const float scale = 0.125f;

    #pragma unroll
    for (int ii = 0; ii < 2; ++ii) {
        const int it = wv * 2 + ii;
        f32x4 s[8] = {};
        #pragma unroll
        for (int kt = 0; kt < 2; ++kt) {
            bf16x8 a = *(const bf16x8*)(Q + base + (size_t)(it * 16 + c) * DD + kt * 32 + quad * 8);
            #pragma unroll
            for (int jt = 0; jt < 8; ++jt) {
                bf16x8 bb = *(const bf16x8*)(K + base + (size_t)(jt * 16 + c) * DD + kt * 32 + quad * 8);
                s[jt] = mfma16(a, bb, s[jt]);
            }
        }
        #pragma unroll
        for (int jt = 0; jt < 8; ++jt) s[jt] *= scale;

        #pragma unroll
        for (int r = 0; r < 4; ++r) {
            float m = -1e30f;
            #pragma unroll
            for (int jt = 0; jt < 8; ++jt) m = fmaxf(m, s[jt][r]);
            #pragma unroll
            for (int off = 1; off < 16; off <<= 1) m = fmaxf(m, __shfl_xor(m, off));
            float p[8], sum = 0.f;
            #pragma unroll
            for (int jt = 0; jt < 8; ++jt) { p[jt] = __expf(s[jt][r] - m); sum += p[jt]; }
            #pragma unroll
            for (int off = 1; off < 16; off <<= 1) sum += __shfl_xor(sum, off);
            float inv = 1.0f / sum;
            int row = it * 16 + quad * 4 + r;
            #pragma unroll
            for (int jt = 0; jt < 8; ++jt) pbuf[row][jt * 16 + c] = (bf16_t)(p[jt] * inv);
        }
    }

    __syncthreads();

    #pragma unroll
    for (int ii = 0; ii < 2; ++ii) {
        const int it = wv * 2 + ii;
        f32x4 o[4] = {};
        #pragma unroll
        for (int kt = 0; kt < 4; ++kt) {
            bf16x8 a = *(const bf16x8*)&pbuf[it * 16 + c][kt * 32 + quad * 8];
            #pragma unroll
            for (int dt = 0; dt < 4; ++dt) {
                bf16x8 bb = *(const bf16x8*)&vtb[dt * 16 + c][kt * 32 + quad * 8];
                o[dt] = mfma16(a, bb, o[dt]);
            }
        }
        #pragma unroll
        for (int dt = 0; dt < 4; ++dt)
            #pragma unroll
            for (int r = 0; r < 4; ++r)
                ctx[base + (size_t)(it * 16 + quad * 4 + r) * DD + dt * 16 + c] = (bf16_t)(o[dt][r]);
    }
}

// ---------------- global-token attention (unchanged, verified) ----------------
__global__ __launch_bounds__(256) void attn_global(const bf16_t* __restrict__ Q,
                                                   const bf16_t* __restrict__ K,
                                                   const bf16_t* __restrict__ V,
                                                   const int* __restrict__ gidx,
                                                   bf16_t* __restrict__ ctx) {
    const int h = blockIdx.x, b = blockIdx.y;
    const int tid = threadIdx.x;

    __shared__ float qs[NG][HD], ks[NG][HD], vs[NG][HD];
    __shared__ float sc[NG][NG + 1];
    __shared__ int gi[NG];

    if (tid < NG) gi[tid] = gidx[tid];
    __syncthreads();

    for (int e = tid; e < NG * HD; e += 256) {
        int i = e >> 6, d = e & 63;
        size_t off = ((size_t)b * SS + gi[i]) * DD + (size_t)h * HD + d;
        qs[i][d] = (float)Q[off];
        ks[i][d] = (float)K[off];
        vs[i][d] = (float)V[off];
    }
    __syncthreads();

    for (int e = tid; e < NG * NG; e += 256) {
        int i = e >> 5, j = e & 31;
        float s = 0.f;
        #pragma unroll 8
        for (int d = 0; d < HD; ++d) s += qs[i][d] * ks[j][d];
        sc[i][j] = s * 0.125f;
    }
    __syncthreads();

    if (tid < NG) {
        float m = -1e30f;
        for (int j = 0; j < NG; ++j) m = fmaxf(m, sc[tid][j]);
        float sum = 0.f;
        for (int j = 0; j < NG; ++j) { float p = __expf(sc[tid][j] - m); sc[tid][j] = p; sum += p; }
        float inv = 1.f / sum;
        for (int j = 0; j < NG; ++j) sc[tid][j] *= inv;
    }
    __syncthreads();

    for (int e = tid; e < NG * HD; e += 256) {
        int i = e >> 6, d = e & 63;
        float o = 0.f;
        #pragma unroll 8
        for (int j = 0; j < NG; ++j) o += sc[i][j] * vs[j][d];
        ctx[((size_t)b * SS + gi[i]) * DD + (size_t)h * HD + d] = (bf16_t)o;
    }
}

extern "C" void kernel_launch(void* const* d_in, const int* in_sizes, int n_in,
                              void* d_out, int out_size, void* d_ws, size_t ws_size,
                              hipStream_t stream) {
    const void* query = d_in[0];
    const void* key_  = d_in[1];
    const void* value = d_in[2];
    const void* Wq = d_in[3];  const void* bq = d_in[4];
    const void* Wk = d_in[5];  const void* bk = d_in[6];
    const void* Wv = d_in[7];  const void* bv = d_in[8];
    const void* Wo = d_in[9];  const void* bo = d_in[10];
    const int* gidx = (const int*)d_in[11];

    const size_t nTok = (size_t)DB * SS * DD;   // 16,777,216 elems
    const size_t nW   = (size_t)DD * DD;        // 1,048,576 elems

    // ws layout (~96 MB, round-2-proven budget):
    //   [0,4)        flag
    //   [256,16640)  bias f32[4096]
    //   [32768, +32MB)   Xh (reused per projection; later Y bf16)
    //   [+32MB, +64MB)   Qp
    //   [+64MB, +96MB)   Kp
    int*    flag    = (int*)d_ws;
    float*  biasbuf = (float*)((char*)d_ws + 256);
    bf16_t* Xh      = (bf16_t*)((char*)d_ws + 32768);
    bf16_t* Qp      = Xh + nTok;
    bf16_t* Kp      = Qp + nTok;
    bf16_t* Ybf     = Xh;  // final GEMM output (Xh dead by then)

    // d_out (64 MB) doubles as scratch:
    //   lo 32MB: W slot for projections, then ctx
    //   hi 32MB: Vp, then W slot for the output projection
    bf16_t* WloH = (bf16_t*)d_out;
    bf16_t* WloL = WloH + nW;
    bf16_t* ctx  = (bf16_t*)d_out;
    bf16_t* Vp   = (bf16_t*)d_out + nTok;
    bf16_t* WhiH = Vp;
    bf16_t* WhiL = WhiH + nW;

    detect_dtype<<<1, 64, 0, stream>>>((const unsigned short*)query, flag);
    cvt_bias<<<16, 256, 0, stream>>>(bq, bk, bv, bo, biasbuf, flag);

    dim3 gg(128, 8);  // 128x128 tiles over 16384x1024

    cvt_w<<<1024, 256, 0, stream>>>(Wq, WloH, WloL, flag);
    cvt_x<<<16384, 256, 0, stream>>>(query, Xh, flag);
    gemm2<<<gg, 256, 0, stream>>>(Xh, WloH, WloL, biasbuf + 0, Qp);

    cvt_w<<<1024, 256, 0, stream>>>(Wk, WloH, WloL, flag);
    cvt_x<<<16384, 256, 0, stream>>>(key_, Xh, flag);
    gemm2<<<gg, 256, 0, stream>>>(Xh, WloH, WloL, biasbuf + 1024, Kp);

    cvt_w<<<1024, 256, 0, stream>>>(Wv, WloH, WloL, flag);
    cvt_x<<<16384, 256, 0, stream>>>(value, Xh, flag);
    gemm2<<<gg, 256, 0, stream>>>(Xh, WloH, WloL, biasbuf + 2048, Vp);

    attn_local<<<dim3(NW, HH, DB), 256, 0, stream>>>(Qp, Kp, Vp, ctx);
    attn_global<<<dim3(HH, DB), 256, 0, stream>>>(Qp, Kp, Vp, gidx, ctx);

    cvt_w<<<1024, 256, 0, stream>>>(Wo, WhiH, WhiL, flag);
    gemm2<<<gg, 256, 0, stream>>>(ctx, WhiH, WhiL, biasbuf + 3072, Ybf);
    expand_out<<<16384, 256, 0, stream>>>(Ybf, d_out, flag);
}